// Round 12
// baseline (222.893 us; speedup 1.0000x reference)
//
#include <hip/hip_runtime.h>
#include <hip/hip_bf16.h>

// GAT on two 512-node cliques + bipartite cross edges, 5 GATConv layers.
// Dense-in-disguise edges: "inside" = clique within each set (+self),
// "cross" = full bipartite to opposite set (+self).
//
// R12: prep dispatch removed (7 -> 6 dispatches). Every kernel self-detects
// the input dtype (f32 vs bf16, runtime probe) and converts its own tiny
// W-column / attention-vector operands. Layer 1 reads raw desc rows
// directly (row-major, 16B vector loads -> deep MLP, and saves the
// prep-transpose xt roundtrip). Layers 2-4 unchanged from R11 (absmax 0):
// separable softmax via counting sort + shfl scans, 16-deep load batches.
// All internal f32; input/output dtype runtime-detected f32/bf16.

typedef __hip_bfloat16 bf16;

__device__ __forceinline__ float b2f(bf16 x) { return __bfloat162float(x); }

__device__ __forceinline__ int detect_bf16(const void* desc1) {
  const unsigned* u = (const unsigned*)desc1;
  int hits = 0;
#pragma unroll 8
  for (int i = 0; i < 256; ++i) {
    unsigned e = (u[i] >> 7) & 0xFFu;
    hits += (e >= 100u && e <= 140u) ? 1 : 0;
  }
  return hits >= 200 ? 1 : 0;
}

__device__ __forceinline__ float load_in(const void* p, int i, int bf) {
  return bf ? b2f(((const bf16*)p)[i]) : ((const float*)p)[i];
}

__device__ __forceinline__ float bflo(unsigned u) {
  return __uint_as_float(u << 16);
}
__device__ __forceinline__ float bfhi(unsigned u) {
  return __uint_as_float(u & 0xffff0000u);
}

// ------------------------------------------------------- fused GAT layer ----
// grid 256 = (S<<7)|hd, 512 threads.  Sources = set S; dst = S (inside) or
// 1-S (cross).  Thread tid owns src node S*512+tid AND dst node D*512+tid.
// RAW=1 (layer 1 only, inside): x read directly from desc1/desc2 rows.
template <int CROSS, int RAW>
__global__ __launch_bounds__(512, 2) void layer_kernel(
    const void* __restrict__ rawx1, const void* __restrict__ rawx2,
    const float* __restrict__ xt_in, float* __restrict__ xt_out,
    const void* __restrict__ Wraw, const void* __restrict__ asr,
    const void* __restrict__ adr,  const void* __restrict__ brw) {
  __shared__ float    wcol[128];     // this head's W column (f32)
  __shared__ float    sS[512];       // bucket-ordered s
  __shared__ float    sH[512];       // bucket-ordered h
  __shared__ unsigned hA[512];       // histogram
  __shared__ unsigned ISb[512];      // inclusive scan of hist
  __shared__ unsigned binNext[512];
  __shared__ float2   PRE[512];      // incl. prefix of (e2, e2*h), sorted ord
  __shared__ float2   SUF[512];      // incl. suffix of (e1, e1*h), sorted ord
  __shared__ float    red[16];
  __shared__ unsigned wTot[8];
  __shared__ float2   preTot[8];
  __shared__ float2   sufTot[8];

  const int tid  = threadIdx.x;
  const int lane = tid & 63;
  const int wave = tid >> 6;
  const int hd   = blockIdx.x & 127;
  const int S    = blockIdx.x >> 7;
  const int D    = CROSS ? (1 - S) : S;
  const int bf   = detect_bf16(rawx1);

  if (tid < 128) wcol[tid] = load_in(Wraw, tid * 128 + hd, bf);
  const float a_src = load_in(asr, hd, bf);
  const float a_dst = load_in(adr, hd, bf);
  const float bias  = load_in(brw, hd, bf);
  __syncthreads();                                        // (0) wcol ready

  // Phase A: h column for this head.
  float h_src, h_dst;
  if (RAW) {
    // read own raw row (row-major [n][128]); RAW is inside-only => D==S.
    float acc0 = 0.f, acc1 = 0.f;
    const char* rowb = (const char*)((S == 0) ? rawx1 : rawx2);
    if (bf) {
      const uint4* rp = (const uint4*)(rowb + (size_t)tid * 256);
      for (int g = 0; g < 2; ++g) {
        uint4 q[8];
#pragma unroll
        for (int u = 0; u < 8; ++u) q[u] = rp[g * 8 + u];
#pragma unroll
        for (int u = 0; u < 8; ++u) {
          const int ch = (g * 8 + u) * 8;
          acc0 = fmaf(bflo(q[u].x), wcol[ch + 0], acc0);
          acc1 = fmaf(bfhi(q[u].x), wcol[ch + 1], acc1);
          acc0 = fmaf(bflo(q[u].y), wcol[ch + 2], acc0);
          acc1 = fmaf(bfhi(q[u].y), wcol[ch + 3], acc1);
          acc0 = fmaf(bflo(q[u].z), wcol[ch + 4], acc0);
          acc1 = fmaf(bfhi(q[u].z), wcol[ch + 5], acc1);
          acc0 = fmaf(bflo(q[u].w), wcol[ch + 6], acc0);
          acc1 = fmaf(bfhi(q[u].w), wcol[ch + 7], acc1);
        }
      }
    } else {
      const float4* rp = (const float4*)(rowb + (size_t)tid * 512);
      for (int g = 0; g < 4; ++g) {
        float4 q[8];
#pragma unroll
        for (int u = 0; u < 8; ++u) q[u] = rp[g * 8 + u];
#pragma unroll
        for (int u = 0; u < 8; ++u) {
          const int ch = (g * 8 + u) * 4;
          acc0 = fmaf(q[u].x, wcol[ch + 0], acc0);
          acc1 = fmaf(q[u].y, wcol[ch + 1], acc1);
          acc0 = fmaf(q[u].z, wcol[ch + 2], acc0);
          acc1 = fmaf(q[u].w, wcol[ch + 3], acc1);
        }
      }
    }
    h_src = acc0 + acc1;
    h_dst = h_src;
  } else {
    float accS0 = 0.f, accS1 = 0.f, accD0 = 0.f, accD1 = 0.f;
    const float* baseS = xt_in + S * 512 + tid;
    const float* baseD = xt_in + D * 512 + tid;
    for (int kk = 0; kk < 128; kk += 16) {
      float xs[16], xd[16];
#pragma unroll
      for (int u = 0; u < 16; ++u) {
        xs[u] = baseS[(kk + u) * 1024];
        if (CROSS) xd[u] = baseD[(kk + u) * 1024];
      }
#pragma unroll
      for (int u = 0; u < 16; u += 2) {
        float w0 = wcol[kk + u];
        float w1 = wcol[kk + u + 1];
        accS0 = fmaf(xs[u],     w0, accS0);
        accS1 = fmaf(xs[u + 1], w1, accS1);
        if (CROSS) {
          accD0 = fmaf(xd[u],     w0, accD0);
          accD1 = fmaf(xd[u + 1], w1, accD1);
        }
      }
    }
    h_src = accS0 + accS1;
    h_dst = CROSS ? (accD0 + accD1) : h_src;
  }
  const float s_own = h_src * a_src;
  const float d_own = h_dst * a_dst;

  // B1: block min/max of s (wave shuffle + LDS combine); zero hist.
  {
    float mnw = s_own, mxw = s_own;
#pragma unroll
    for (int off = 32; off > 0; off >>= 1) {
      mnw = fminf(mnw, __shfl_down(mnw, off));
      mxw = fmaxf(mxw, __shfl_down(mxw, off));
    }
    if (lane == 0) { red[wave] = mnw; red[8 + wave] = mxw; }
  }
  hA[tid] = 0;
  binNext[tid] = 0;
  __syncthreads();                                        // (1)
  const float mn = fminf(fminf(fminf(red[0], red[1]), fminf(red[2], red[3])),
                         fminf(fminf(red[4], red[5]), fminf(red[6], red[7])));
  const float mx = fmaxf(fmaxf(fmaxf(red[8], red[9]), fmaxf(red[10], red[11])),
                         fmaxf(fmaxf(red[12], red[13]), fmaxf(red[14], red[15])));
  const float scale = 512.0f / fmaxf(mx - mn, 1e-20f);

  // B2: histogram (bin(x) monotone non-decreasing).
  const int myBin = (int)fminf(fmaxf((s_own - mn) * scale, 0.0f), 511.0f);
  atomicAdd(&hA[myBin], 1u);
  __syncthreads();                                        // (2)

  // B3: inclusive scan of hist via wave shuffles + wave-total exchange.
  {
    unsigned v = hA[tid];
#pragma unroll
    for (int off = 1; off < 64; off <<= 1) {
      unsigned u = __shfl_up(v, off);
      if (lane >= off) v += u;
    }
    if (lane == 63) wTot[wave] = v;
    __syncthreads();                                      // (3)
    unsigned pre = 0;
#pragma unroll
    for (int w = 0; w < 8; ++w) pre += (w < wave) ? wTot[w] : 0u;
    ISb[tid] = v + pre;
    __syncthreads();                                      // (4)
  }

  // B4: scatter into bucket-ordered arrays (order within bucket free).
  {
    unsigned base = myBin ? ISb[myBin - 1] : 0u;
    unsigned pos = base + atomicAdd(&binNext[myBin], 1u);
    sS[pos] = s_own;
    sH[pos] = h_src;
  }
  __syncthreads();                                        // (5)

  // B5: exps + prefix(e2,e2h) / suffix(e1,e1h) via wave shuffles.
  {
    const float sv = sS[tid];
    const float hv = sH[tid];
    const float e1 = __expf(sv), e2 = __expf(0.2f * sv);
    float p0 = e2, p1 = e2 * hv;     // prefix pair
    float q0 = e1, q1 = e1 * hv;     // suffix pair
#pragma unroll
    for (int off = 1; off < 64; off <<= 1) {
      float u0 = __shfl_up(p0, off), u1 = __shfl_up(p1, off);
      if (lane >= off) { p0 += u0; p1 += u1; }
      float v0 = __shfl_down(q0, off), v1 = __shfl_down(q1, off);
      if (lane + off < 64) { q0 += v0; q1 += v1; }
    }
    if (lane == 63) preTot[wave] = make_float2(p0, p1);
    if (lane == 0)  sufTot[wave] = make_float2(q0, q1);
    __syncthreads();                                      // (6)
    float a0 = 0.f, a1 = 0.f, b0 = 0.f, b1 = 0.f;
#pragma unroll
    for (int w = 0; w < 8; ++w) {
      float2 pt = preTot[w], st = sufTot[w];
      if (w < wave) { a0 += pt.x; a1 += pt.y; }
      if (w > wave) { b0 += st.x; b1 += st.y; }
    }
    PRE[tid] = make_float2(p0 + a0, p1 + a1);
    SUF[tid] = make_float2(q0 + b0, q1 + b1);
    __syncthreads();                                      // (7)
  }

  // B7: per destination: bucket lookup + boundary-exact combine.
  {
    const float theta = -d_own;
    int b = (int)fminf(fmaxf((theta - mn) * scale, 0.0f), 511.0f);
    unsigned k0 = b ? ISb[b - 1] : 0u;  // elems in buckets < b: s < theta
    unsigned k1 = ISb[b];               // elems in buckets <= b
    float F1 = __expf(d_own), F2 = __expf(0.2f * d_own);
    float P2 = 0.f, P2h = 0.f, S1 = 0.f, S1h = 0.f;
    if (k0 > 0)   { float2 t2 = PRE[k0 - 1]; P2 = t2.x; P2h = t2.y; }
    if (k1 < 512) { float2 t2 = SUF[k1];     S1 = t2.x; S1h = t2.y; }
    float den = F1 * S1 + F2 * P2;
    float num = F1 * S1h + F2 * P2h;
    for (unsigned e = k0; e < k1; ++e) {  // boundary bucket: exact compare
      float se = sS[e], he = sH[e];
      float p = (se >= theta) ? F1 * __expf(se) : F2 * __expf(0.2f * se);
      den += p;
      num = fmaf(p, he, num);
    }
    if (CROSS) {  // self-loop: dst node's own source score
      float t = h_dst * a_src + d_own;
      float p = __expf(fmaxf(t, 0.2f * t));
      den += p;
      num = fmaf(p, h_dst, num);
    }
    float o = num / (den + 1e-16f) + bias;
    o = (o > 0.f) ? o : expm1f(o);  // ELU
    xt_out[hd * 1024 + D * 512 + tid] = o;
  }
}

// ----------------------------------------------------- final layer: mm2 ----
// grid 512 x 256: 2 rows x 128 cols per block.  h2 = x@W2, s2/d2 row dots.
__global__ __launch_bounds__(256, 2) void mm2_kernel(
    const void* __restrict__ rawd1, const float* __restrict__ xt_in,
    const void* __restrict__ W2raw, const void* __restrict__ as2r,
    const void* __restrict__ ad2r,
    float* __restrict__ h2, float* __restrict__ s2, float* __restrict__ d2v) {
  __shared__ float rs[256], rd[256];
  const int bf = detect_bf16(rawd1);
  const int tid = threadIdx.x;
  const int row = blockIdx.x * 2 + (tid >> 7);
  const int c = tid & 127;
  float acc0 = 0.f, acc1 = 0.f;
  if (bf) {
    const unsigned short* W2u = (const unsigned short*)W2raw;
    for (int kk = 0; kk < 128; kk += 16) {
      float xb[16];
#pragma unroll
      for (int u = 0; u < 16; ++u) xb[u] = xt_in[(kk + u) * 1024 + row];
#pragma unroll
      for (int u = 0; u < 16; u += 2) {
        float w0 = __uint_as_float(((unsigned)W2u[(kk + u) * 128 + c]) << 16);
        float w1 = __uint_as_float(((unsigned)W2u[(kk + u + 1) * 128 + c]) << 16);
        acc0 = fmaf(xb[u],     w0, acc0);
        acc1 = fmaf(xb[u + 1], w1, acc1);
      }
    }
  } else {
    const float* W2f = (const float*)W2raw;
    for (int kk = 0; kk < 128; kk += 16) {
      float xb[16];
#pragma unroll
      for (int u = 0; u < 16; ++u) xb[u] = xt_in[(kk + u) * 1024 + row];
#pragma unroll
      for (int u = 0; u < 16; u += 2) {
        acc0 = fmaf(xb[u],     W2f[(kk + u) * 128 + c],     acc0);
        acc1 = fmaf(xb[u + 1], W2f[(kk + u + 1) * 128 + c], acc1);
      }
    }
  }
  float acc = acc0 + acc1;
  h2[row * 128 + c] = acc;
  rs[tid] = acc * load_in(as2r, c, bf);  // a_src2
  rd[tid] = acc * load_in(ad2r, c, bf);  // a_dst2
  __syncthreads();
  for (int off = 64; off > 0; off >>= 1) {
    if ((tid & 127) < off) { rs[tid] += rs[tid + off]; rd[tid] += rd[tid + off]; }
    __syncthreads();
  }
  if ((tid & 127) == 0) {
    s2[row] = rs[tid];
    d2v[row] = rd[tid];
  }
}

// ---------------------------------------------------- final layer: attn ----
// Final conv: heads=1, ch=128, cross edges + self, no ELU, +b2.
__global__ __launch_bounds__(256, 1) void att2_kernel(
    const void* __restrict__ rawd1, const float* __restrict__ h2,
    const float* __restrict__ s2, const float* __restrict__ d2v,
    const void* __restrict__ b2r, void* __restrict__ out) {
  __shared__ __align__(16) float pT[512 * 4];  // pT[j*4 + ld]
  const int bf = detect_bf16(rawd1);
  const int tid = threadIdx.x;
  const int dstBase = blockIdx.x * 4;
  const int srcBase = (dstBase < 512) ? 512 : 0;  // cross edges

  for (int e = tid; e < 2048; e += 256) {
    int j = e >> 2, ld = e & 3;
    float t = s2[srcBase + j] + d2v[dstBase + ld];
    pT[e] = __expf(fmaxf(t, 0.2f * t));
  }
  __syncthreads();

  const int c = tid & 127;
  const int g = tid >> 7;            // 0 or 1 -> dst pair
  const int i0 = dstBase + 2 * g, i1 = i0 + 1;
  float den0 = 0.f, num0 = 0.f, den1 = 0.f, num1 = 0.f;
  const float* hrow = h2 + srcBase * 128 + c;
  for (int j0 = 0; j0 < 512; j0 += 8) {
    float hb[8];
#pragma unroll
    for (int u = 0; u < 8; ++u) hb[u] = hrow[(j0 + u) * 128];
#pragma unroll
    for (int u = 0; u < 8; ++u) {
      float2 pv = *(const float2*)(pT + (j0 + u) * 4 + 2 * g);
      den0 += pv.x; num0 = fmaf(pv.x, hb[u], num0);
      den1 += pv.y; num1 = fmaf(pv.y, hb[u], num1);
    }
  }
  // self-loops
  float ts0 = s2[i0] + d2v[i0];
  float ps0 = __expf(fmaxf(ts0, 0.2f * ts0));
  den0 += ps0; num0 = fmaf(ps0, h2[i0 * 128 + c], num0);
  float ts1 = s2[i1] + d2v[i1];
  float ps1 = __expf(fmaxf(ts1, 0.2f * ts1));
  den1 += ps1; num1 = fmaf(ps1, h2[i1 * 128 + c], num1);

  float b2c = load_in(b2r, c, bf);
  float o0 = num0 / (den0 + 1e-16f) + b2c;
  float o1 = num1 / (den1 + 1e-16f) + b2c;
  if (bf) {
    ((bf16*)out)[i0 * 128 + c] = __float2bfloat16(o0);
    ((bf16*)out)[i1 * 128 + c] = __float2bfloat16(o1);
  } else {
    ((float*)out)[i0 * 128 + c] = o0;
    ((float*)out)[i1 * 128 + c] = o1;
  }
}

// ------------------------------------------------------------- launcher ----
extern "C" void kernel_launch(void* const* d_in, const int* in_sizes, int n_in,
                              void* d_out, int out_size, void* d_ws, size_t ws_size,
                              hipStream_t stream) {
  (void)in_sizes; (void)n_in; (void)out_size; (void)ws_size;
  float* ws  = (float*)d_ws;
  float* xtA = ws;            // 131072
  float* xtB = ws + 131072;   // 131072
  float* h2  = ws + 262144;   // 131072
  float* s2  = ws + 393216;   // 1024
  float* d2v = ws + 394240;   // 1024

  const void* desc1 = d_in[0];
  const void* desc2 = d_in[1];
  const void* W1    = d_in[2];
  const void* as1   = d_in[3];
  const void* ad1   = d_in[4];
  const void* b1    = d_in[5];
  const void* W2    = d_in[6];
  const void* as2   = d_in[7];
  const void* ad2   = d_in[8];
  const void* b2    = d_in[9];

  // L1 inside (RAW: reads desc rows directly)
  layer_kernel<0, 1><<<256, 512, 0, stream>>>(desc1, desc2, xtA, xtB,
                                              W1, as1, ad1, b1);
  // L2 cross
  layer_kernel<1, 0><<<256, 512, 0, stream>>>(desc1, desc2, xtB, xtA,
                                              W1, as1, ad1, b1);
  // L3 inside
  layer_kernel<0, 0><<<256, 512, 0, stream>>>(desc1, desc2, xtA, xtB,
                                              W1, as1, ad1, b1);
  // L4 cross
  layer_kernel<1, 0><<<256, 512, 0, stream>>>(desc1, desc2, xtB, xtA,
                                              W1, as1, ad1, b1);
  // final layer
  mm2_kernel<<<512, 256, 0, stream>>>(desc1, xtA, W2, as2, ad2, h2, s2, d2v);
  att2_kernel<<<256, 256, 0, stream>>>(desc1, h2, s2, d2v, b2, d_out);
}

// Round 13
// 168.916 us; speedup vs baseline: 1.3196x; 1.3196x over previous
//
#include <hip/hip_runtime.h>
#include <hip/hip_bf16.h>

// GAT on two 512-node cliques + bipartite cross edges, 5 GATConv layers.
// Dense-in-disguise edges: "inside" = clique within each set (+self),
// "cross" = full bipartite to opposite set (+self).
//
// R13 = R11 (best, 180us, absmax 0) + packed float4 activation layout.
// Inter-layer activations stored as xt4[c/4][n][4] so phase A reads are
// 32 float4 loads/thread (4x fewer VMEM instrs, coalesced 16B/lane)
// instead of 128 scalar dword loads. Accumulation order preserved ->
// bit-identical results. Dtype detect/convert stays confined to prep
// (R12's runtime-dual-path in hot kernels caused VGPR 24->128 + 34MB
// spill traffic/layer — reverted).
// All internal f32; input/output dtype runtime-detected f32/bf16.

typedef __hip_bfloat16 bf16;

__device__ __forceinline__ float b2f(bf16 x) { return __bfloat162float(x); }

__device__ __forceinline__ int detect_bf16(const void* desc1) {
  const unsigned* u = (const unsigned*)desc1;
  int hits = 0;
#pragma unroll 8
  for (int i = 0; i < 256; ++i) {
    unsigned e = (u[i] >> 7) & 0xFFu;
    hits += (e >= 100u && e <= 140u) ? 1 : 0;
  }
  return hits >= 200 ? 1 : 0;
}

__device__ __forceinline__ float load_in(const void* p, int i, int bf) {
  return bf ? b2f(((const bf16*)p)[i]) : ((const float*)p)[i];
}

// ---------------------------------------------------------------- prep ----
// xt written in packed layout: xt[((c>>2)*1024 + n)*4 + (c&3)].
__global__ __launch_bounds__(256) void prep_kernel(
    const void* __restrict__ desc1, const void* __restrict__ desc2,
    const void* __restrict__ W1,   const void* __restrict__ as1,
    const void* __restrict__ ad1,  const void* __restrict__ b1,
    const void* __restrict__ W2,   const void* __restrict__ as2,
    const void* __restrict__ ad2,  const void* __restrict__ b2,
    float* __restrict__ xt, float* __restrict__ W1f, float* __restrict__ W2f,
    float* __restrict__ vecs, int* __restrict__ flag) {
  const int bf = detect_bf16(desc1);
  if (blockIdx.x == 0 && threadIdx.x == 0) *flag = bf;
  const int total = 131072 + 16384 + 16384 + 6 * 128;
  for (int idx = blockIdx.x * blockDim.x + threadIdx.x; idx < total;
       idx += gridDim.x * blockDim.x) {
    if (idx < 131072) {
      int n = idx & 1023, c = idx >> 10;
      float v = (n < 512) ? load_in(desc1, n * 128 + c, bf)
                          : load_in(desc2, (n - 512) * 128 + c, bf);
      xt[((c >> 2) * 1024 + n) * 4 + (c & 3)] = v;
    } else if (idx < 147456) {
      W1f[idx - 131072] = load_in(W1, idx - 131072, bf);
    } else if (idx < 163840) {
      W2f[idx - 147456] = load_in(W2, idx - 147456, bf);
    } else {
      int i = idx - 163840, o = i & 127;
      float v;
      if      (i < 128) v = load_in(as1, o, bf);
      else if (i < 256) v = load_in(ad1, o, bf);
      else if (i < 384) v = load_in(b1, o, bf);
      else if (i < 512) v = load_in(as2, o, bf);
      else if (i < 640) v = load_in(ad2, o, bf);
      else              v = load_in(b2, o, bf);
      vecs[i] = v;
    }
  }
}

// ------------------------------------------------------- fused GAT layer ----
// grid 256 = (S<<7)|hd, 512 threads.  Sources = set S; dst = S (inside) or
// 1-S (cross).  Thread tid owns src node S*512+tid AND dst node D*512+tid.
template <int CROSS>
__global__ __launch_bounds__(512, 2) void layer_kernel(
    const float* __restrict__ xt_in, float* __restrict__ xt_out,
    const float* __restrict__ Wf, const float* __restrict__ vecs) {
  __shared__ float    sS[512];       // bucket-ordered s
  __shared__ float    sH[512];       // bucket-ordered h
  __shared__ unsigned hA[512];       // histogram
  __shared__ unsigned ISb[512];      // inclusive scan of hist
  __shared__ unsigned binNext[512];
  __shared__ float2   PRE[512];      // incl. prefix of (e2, e2*h), sorted ord
  __shared__ float2   SUF[512];      // incl. suffix of (e1, e1*h), sorted ord
  __shared__ float    red[16];
  __shared__ unsigned wTot[8];
  __shared__ float2   preTot[8];
  __shared__ float2   sufTot[8];

  const int tid  = threadIdx.x;
  const int lane = tid & 63;
  const int wave = tid >> 6;
  const int hd   = blockIdx.x & 127;
  const int S    = blockIdx.x >> 7;
  const int D    = CROSS ? (1 - S) : S;
  const float a_src = vecs[hd], a_dst = vecs[128 + hd], bias = vecs[256 + hd];

  // Phase A: h column for this head.  Packed layout: 32 float4 loads/thread
  // (8-deep batches), channels 4*cc..4*cc+3 per float4.
  float accS0 = 0.f, accS1 = 0.f, accD0 = 0.f, accD1 = 0.f;
  {
    const float4* x4 = (const float4*)xt_in;
    const int nS = S * 512 + tid;
    const int nD = D * 512 + tid;
    for (int cc = 0; cc < 32; cc += 8) {
      float4 xs[8], xd[8];
#pragma unroll
      for (int u = 0; u < 8; ++u) {
        xs[u] = x4[(cc + u) * 1024 + nS];
        if (CROSS) xd[u] = x4[(cc + u) * 1024 + nD];
      }
#pragma unroll
      for (int u = 0; u < 8; ++u) {
        const int k = (cc + u) * 4;
        const float w0 = Wf[k * 128 + hd];
        const float w1 = Wf[(k + 1) * 128 + hd];
        const float w2 = Wf[(k + 2) * 128 + hd];
        const float w3 = Wf[(k + 3) * 128 + hd];
        accS0 = fmaf(xs[u].x, w0, accS0);
        accS1 = fmaf(xs[u].y, w1, accS1);
        accS0 = fmaf(xs[u].z, w2, accS0);
        accS1 = fmaf(xs[u].w, w3, accS1);
        if (CROSS) {
          accD0 = fmaf(xd[u].x, w0, accD0);
          accD1 = fmaf(xd[u].y, w1, accD1);
          accD0 = fmaf(xd[u].z, w2, accD0);
          accD1 = fmaf(xd[u].w, w3, accD1);
        }
      }
    }
  }
  const float h_src = accS0 + accS1;
  const float h_dst = CROSS ? (accD0 + accD1) : h_src;
  const float s_own = h_src * a_src;
  const float d_own = h_dst * a_dst;

  // B1: block min/max of s (wave shuffle + LDS combine); zero hist.
  {
    float mnw = s_own, mxw = s_own;
#pragma unroll
    for (int off = 32; off > 0; off >>= 1) {
      mnw = fminf(mnw, __shfl_down(mnw, off));
      mxw = fmaxf(mxw, __shfl_down(mxw, off));
    }
    if (lane == 0) { red[wave] = mnw; red[8 + wave] = mxw; }
  }
  hA[tid] = 0;
  binNext[tid] = 0;
  __syncthreads();                                        // (1)
  const float mn = fminf(fminf(fminf(red[0], red[1]), fminf(red[2], red[3])),
                         fminf(fminf(red[4], red[5]), fminf(red[6], red[7])));
  const float mx = fmaxf(fmaxf(fmaxf(red[8], red[9]), fmaxf(red[10], red[11])),
                         fmaxf(fmaxf(red[12], red[13]), fmaxf(red[14], red[15])));
  const float scale = 512.0f / fmaxf(mx - mn, 1e-20f);

  // B2: histogram (bin(x) monotone non-decreasing).
  const int myBin = (int)fminf(fmaxf((s_own - mn) * scale, 0.0f), 511.0f);
  atomicAdd(&hA[myBin], 1u);
  __syncthreads();                                        // (2)

  // B3: inclusive scan of hist via wave shuffles + wave-total exchange.
  {
    unsigned v = hA[tid];
#pragma unroll
    for (int off = 1; off < 64; off <<= 1) {
      unsigned u = __shfl_up(v, off);
      if (lane >= off) v += u;
    }
    if (lane == 63) wTot[wave] = v;
    __syncthreads();                                      // (3)
    unsigned pre = 0;
#pragma unroll
    for (int w = 0; w < 8; ++w) pre += (w < wave) ? wTot[w] : 0u;
    ISb[tid] = v + pre;
    __syncthreads();                                      // (4)
  }

  // B4: scatter into bucket-ordered arrays (order within bucket free).
  {
    unsigned base = myBin ? ISb[myBin - 1] : 0u;
    unsigned pos = base + atomicAdd(&binNext[myBin], 1u);
    sS[pos] = s_own;
    sH[pos] = h_src;
  }
  __syncthreads();                                        // (5)

  // B5: exps + prefix(e2,e2h) / suffix(e1,e1h) via wave shuffles.
  {
    const float sv = sS[tid];
    const float hv = sH[tid];
    const float e1 = __expf(sv), e2 = __expf(0.2f * sv);
    float p0 = e2, p1 = e2 * hv;     // prefix pair
    float q0 = e1, q1 = e1 * hv;     // suffix pair
#pragma unroll
    for (int off = 1; off < 64; off <<= 1) {
      float u0 = __shfl_up(p0, off), u1 = __shfl_up(p1, off);
      if (lane >= off) { p0 += u0; p1 += u1; }
      float v0 = __shfl_down(q0, off), v1 = __shfl_down(q1, off);
      if (lane + off < 64) { q0 += v0; q1 += v1; }
    }
    if (lane == 63) preTot[wave] = make_float2(p0, p1);
    if (lane == 0)  sufTot[wave] = make_float2(q0, q1);
    __syncthreads();                                      // (6)
    float a0 = 0.f, a1 = 0.f, b0 = 0.f, b1 = 0.f;
#pragma unroll
    for (int w = 0; w < 8; ++w) {
      float2 pt = preTot[w], st = sufTot[w];
      if (w < wave) { a0 += pt.x; a1 += pt.y; }
      if (w > wave) { b0 += st.x; b1 += st.y; }
    }
    PRE[tid] = make_float2(p0 + a0, p1 + a1);
    SUF[tid] = make_float2(q0 + b0, q1 + b1);
    __syncthreads();                                      // (7)
  }

  // B7: per destination: bucket lookup + boundary-exact combine.
  {
    const float theta = -d_own;
    int b = (int)fminf(fmaxf((theta - mn) * scale, 0.0f), 511.0f);
    unsigned k0 = b ? ISb[b - 1] : 0u;  // elems in buckets < b: s < theta
    unsigned k1 = ISb[b];               // elems in buckets <= b
    float F1 = __expf(d_own), F2 = __expf(0.2f * d_own);
    float P2 = 0.f, P2h = 0.f, S1 = 0.f, S1h = 0.f;
    if (k0 > 0)   { float2 t2 = PRE[k0 - 1]; P2 = t2.x; P2h = t2.y; }
    if (k1 < 512) { float2 t2 = SUF[k1];     S1 = t2.x; S1h = t2.y; }
    float den = F1 * S1 + F2 * P2;
    float num = F1 * S1h + F2 * P2h;
    for (unsigned e = k0; e < k1; ++e) {  // boundary bucket: exact compare
      float se = sS[e], he = sH[e];
      float p = (se >= theta) ? F1 * __expf(se) : F2 * __expf(0.2f * se);
      den += p;
      num = fmaf(p, he, num);
    }
    if (CROSS) {  // self-loop: dst node's own source score
      float t = h_dst * a_src + d_own;
      float p = __expf(fmaxf(t, 0.2f * t));
      den += p;
      num = fmaf(p, h_dst, num);
    }
    float o = num / (den + 1e-16f) + bias;
    o = (o > 0.f) ? o : expm1f(o);  // ELU
    // packed layout: xt_out[((hd>>2)*1024 + node)*4 + (hd&3)]
    xt_out[(((hd >> 2) * 1024) + D * 512 + tid) * 4 + (hd & 3)] = o;
  }
}

// ----------------------------------------------------- final layer: mm2 ----
// grid 512 x 256: 2 rows x 128 cols per block.  h2 = x@W2, s2/d2 row dots.
__global__ __launch_bounds__(256, 2) void mm2_kernel(
    const float* __restrict__ xt_in, const float* __restrict__ W2f,
    const float* __restrict__ vecs, float* __restrict__ h2,
    float* __restrict__ s2, float* __restrict__ d2) {
  __shared__ float rs[256], rd[256];
  const int tid = threadIdx.x;
  const int row = blockIdx.x * 2 + (tid >> 7);
  const int c = tid & 127;
  float acc0 = 0.f, acc1 = 0.f;
  {
    const float4* x4 = (const float4*)xt_in;
    for (int cc = 0; cc < 32; cc += 8) {
      float4 xb[8];
#pragma unroll
      for (int u = 0; u < 8; ++u) xb[u] = x4[(cc + u) * 1024 + row];
#pragma unroll
      for (int u = 0; u < 8; ++u) {
        const int k = (cc + u) * 4;
        acc0 = fmaf(xb[u].x, W2f[k * 128 + c],       acc0);
        acc1 = fmaf(xb[u].y, W2f[(k + 1) * 128 + c], acc1);
        acc0 = fmaf(xb[u].z, W2f[(k + 2) * 128 + c], acc0);
        acc1 = fmaf(xb[u].w, W2f[(k + 3) * 128 + c], acc1);
      }
    }
  }
  float acc = acc0 + acc1;
  h2[row * 128 + c] = acc;
  rs[tid] = acc * vecs[384 + c];  // a_src2
  rd[tid] = acc * vecs[512 + c];  // a_dst2
  __syncthreads();
  for (int off = 64; off > 0; off >>= 1) {
    if ((tid & 127) < off) { rs[tid] += rs[tid + off]; rd[tid] += rd[tid + off]; }
    __syncthreads();
  }
  if ((tid & 127) == 0) {
    s2[row] = rs[tid];
    d2[row] = rd[tid];
  }
}

// ---------------------------------------------------- final layer: attn ----
// Final conv: heads=1, ch=128, cross edges + self, no ELU, +b2.
__global__ __launch_bounds__(256, 1) void att2_kernel(
    const float* __restrict__ h2, const float* __restrict__ s2,
    const float* __restrict__ d2, const float* __restrict__ vecs,
    void* __restrict__ out, const int* __restrict__ flag) {
  __shared__ __align__(16) float pT[512 * 4];  // pT[j*4 + ld]
  const int tid = threadIdx.x;
  const int dstBase = blockIdx.x * 4;
  const int srcBase = (dstBase < 512) ? 512 : 0;  // cross edges

  for (int e = tid; e < 2048; e += 256) {
    int j = e >> 2, ld = e & 3;
    float t = s2[srcBase + j] + d2[dstBase + ld];
    pT[e] = __expf(fmaxf(t, 0.2f * t));
  }
  __syncthreads();

  const int c = tid & 127;
  const int g = tid >> 7;            // 0 or 1 -> dst pair
  const int i0 = dstBase + 2 * g, i1 = i0 + 1;
  float den0 = 0.f, num0 = 0.f, den1 = 0.f, num1 = 0.f;
  const float* hrow = h2 + srcBase * 128 + c;
  for (int j0 = 0; j0 < 512; j0 += 8) {
    float hb[8];
#pragma unroll
    for (int u = 0; u < 8; ++u) hb[u] = hrow[(j0 + u) * 128];
#pragma unroll
    for (int u = 0; u < 8; ++u) {
      float2 pv = *(const float2*)(pT + (j0 + u) * 4 + 2 * g);
      den0 += pv.x; num0 = fmaf(pv.x, hb[u], num0);
      den1 += pv.y; num1 = fmaf(pv.y, hb[u], num1);
    }
  }
  // self-loops
  float ts0 = s2[i0] + d2[i0];
  float ps0 = __expf(fmaxf(ts0, 0.2f * ts0));
  den0 += ps0; num0 = fmaf(ps0, h2[i0 * 128 + c], num0);
  float ts1 = s2[i1] + d2[i1];
  float ps1 = __expf(fmaxf(ts1, 0.2f * ts1));
  den1 += ps1; num1 = fmaf(ps1, h2[i1 * 128 + c], num1);

  float o0 = num0 / (den0 + 1e-16f) + vecs[640 + c];
  float o1 = num1 / (den1 + 1e-16f) + vecs[640 + c];
  if (*flag) {
    ((bf16*)out)[i0 * 128 + c] = __float2bfloat16(o0);
    ((bf16*)out)[i1 * 128 + c] = __float2bfloat16(o1);
  } else {
    ((float*)out)[i0 * 128 + c] = o0;
    ((float*)out)[i1 * 128 + c] = o1;
  }
}

// ------------------------------------------------------------- launcher ----
extern "C" void kernel_launch(void* const* d_in, const int* in_sizes, int n_in,
                              void* d_out, int out_size, void* d_ws, size_t ws_size,
                              hipStream_t stream) {
  (void)in_sizes; (void)n_in; (void)out_size; (void)ws_size;
  float* ws   = (float*)d_ws;
  float* xtA  = ws;            // 131072 (packed float4 layout)
  float* xtB  = ws + 131072;   // 131072 (packed float4 layout)
  float* h2   = ws + 262144;   // 131072 (row-major)
  float* W1f  = ws + 393216;   // 16384
  float* W2f  = ws + 409600;   // 16384
  float* vecs = ws + 425984;   // 768
  float* s2   = ws + 426752;   // 1024
  float* d2   = ws + 427776;   // 1024
  int*   flag = (int*)(ws + 428800);

  prep_kernel<<<64, 256, 0, stream>>>(d_in[0], d_in[1], d_in[2], d_in[3],
                                      d_in[4], d_in[5], d_in[6], d_in[7],
                                      d_in[8], d_in[9], xtA, W1f, W2f, vecs, flag);
  layer_kernel<0><<<256, 512, 0, stream>>>(xtA, xtB, W1f, vecs);  // L1 inside
  layer_kernel<1><<<256, 512, 0, stream>>>(xtB, xtA, W1f, vecs);  // L2 cross
  layer_kernel<0><<<256, 512, 0, stream>>>(xtA, xtB, W1f, vecs);  // L3 inside
  layer_kernel<1><<<256, 512, 0, stream>>>(xtB, xtA, W1f, vecs);  // L4 cross
  mm2_kernel<<<512, 256, 0, stream>>>(xtA, W2f, vecs, h2, s2, d2);
  att2_kernel<<<256, 256, 0, stream>>>(h2, s2, d2, vecs, d_out, flag);
}